// Round 14
// baseline (160.634 us; speedup 1.0000x reference)
//
#include <hip/hip_runtime.h>
#include <hip/hip_bf16.h>

#define THRESH 0.05f
constexpr int B_   = 32;
constexpr int CIN  = 128;
constexpr int COUT = 256;
constexpr int HH   = 56;
constexpr int WW   = 56;
constexpr int HWSZ = HH * WW;            // 3136
constexpr int WELEM = COUT * CIN * 9;    // 294912
constexpr int PADW = 58;                 // padded spatial dim

typedef unsigned short u16;
typedef __attribute__((ext_vector_type(4))) float  f32x4;
typedef __attribute__((ext_vector_type(8))) short  s16x8;
typedef __attribute__((ext_vector_type(4))) int    i32x4;

typedef const __attribute__((address_space(1))) void* gas1;
typedef __attribute__((address_space(3))) void* las3;
typedef const __attribute__((address_space(3))) void* lcv;
#define GLOAD16(gsrc, ldst) \
    __builtin_amdgcn_global_load_lds((gas1)(gsrc), (las3)(ldst), 16, 0, 0)

// opaque LDS vector read: compiler cannot sink/fold/remat
#define DSR(dst, base, byteoff) \
    asm volatile("ds_read_b128 %0, %1 offset:%2" : "=v"(dst) : "v"(base), "i"(byteoff))

static __device__ __forceinline__ u16 f2bf(float f) {
    __hip_bfloat16 h = __float2bfloat16(f);
    return *reinterpret_cast<u16*>(&h);
}
static __device__ __forceinline__ s16x8 as_h(i32x4 v) {
    s16x8 r; __builtin_memcpy(&r, &v, 16); return r;
}

// ---------------------------------------------------------------------------
// Kernel 1: per-block maxabs partials
// ---------------------------------------------------------------------------
__global__ __launch_bounds__(256) void maxabs_part(const float* __restrict__ w,
                                                   float* __restrict__ partial) {
    int tid = threadIdx.x;
    float m = 0.0f;
    for (int i = blockIdx.x * 256 + tid; i < WELEM; i += 256 * 256)
        m = fmaxf(m, fabsf(w[i]));
    #pragma unroll
    for (int off = 32; off > 0; off >>= 1) m = fmaxf(m, __shfl_xor(m, off));
    __shared__ float s[4];
    if ((tid & 63) == 0) s[tid >> 6] = m;
    __syncthreads();
    if (tid == 0) partial[blockIdx.x] = fmaxf(fmaxf(s[0], s[1]), fmaxf(s[2], s[3]));
}

// ---------------------------------------------------------------------------
// Kernel 2: quantize + pack bf16, PERMUTED for the 128-co tile:
// Apack u16 idx = ((cc*2+cot)*128 + row)*288 + tap*32 + swz*8 + e
//   cot = co>>7, row = co&127, ci = cc*32 + kg*8 + e, swz = kg ^ ((row>>1)&3)
// ---------------------------------------------------------------------------
__global__ __launch_bounds__(256) void quant_pack(const float* __restrict__ w,
                                                  const float* __restrict__ partial,
                                                  const float* __restrict__ Wn,
                                                  u16* __restrict__ Apack) {
    int tid = threadIdx.x;
    float m = partial[tid];
    #pragma unroll
    for (int off = 32; off > 0; off >>= 1) m = fmaxf(m, __shfl_xor(m, off));
    __shared__ float s[4];
    if ((tid & 63) == 0) s[tid >> 6] = m;
    __syncthreads();
    const float mx = fmaxf(fmaxf(s[0], s[1]), fmaxf(s[2], s[3]));
    const float wn = Wn[0];

    int idx = blockIdx.x * 256 + tid;          // ((co*128+ci)*9+tap)
    float nw = w[idx] / mx;
    float q  = (nw > -THRESH && nw <= THRESH) ? 0.0f : nw;
    if (q >  THRESH) q =  1.0f;
    if (q < -THRESH) q = -1.0f;
    if (q == -1.0f)  q = wn;

    int tap = idx % 9;
    int r   = idx / 9;
    int ci  = r % CIN;
    int co  = r / CIN;
    int cc  = ci >> 5, lci = ci & 31, kg = lci >> 3, e = lci & 7;
    int cot = co >> 7, row = co & 127;
    int swz = kg ^ ((row >> 1) & 3);
    Apack[(size_t)((cc * 2 + cot) * 128 + row) * 288 + tap * 32 + swz * 8 + e] = f2bf(q);
}

// ---------------------------------------------------------------------------
// Kernel 3: X (NCHW f32) -> padded Xt bf16; pt==0 blocks zero the borders.
// ---------------------------------------------------------------------------
__global__ __launch_bounds__(256) void x_to_bf16t(const float* __restrict__ X,
                                                  u16* __restrict__ XtP) {
    __shared__ u16 T[64 * 136];
    const int b  = blockIdx.x;
    const int n  = b / 49, pt = b - n * 49;
    const int p0 = pt * 64;
    const int tid = threadIdx.x;
    const int ci  = tid >> 1, h2 = tid & 1;

    if (pt == 0) {
        for (int idx = tid; idx < 3648; idx += 256) {
            int c16 = idx & 15, s = idx >> 4;
            int r, c;
            if      (s < 58)  { r = 0;           c = s; }
            else if (s < 116) { r = 57;          c = s - 58; }
            else if (s < 172) { r = s - 116 + 1; c = 0; }
            else              { r = s - 172 + 1; c = 57; }
            size_t site = (size_t)(n * PADW + r) * PADW + c;
            *(s16x8*)(XtP + site * 128 + c16 * 8) = (s16x8){0,0,0,0,0,0,0,0};
        }
    }

    const float* src = X + ((size_t)(n * CIN + ci)) * HWSZ + p0 + h2 * 32;
    #pragma unroll
    for (int j = 0; j < 8; ++j) {
        f32x4 v = *(const f32x4*)(src + j * 4);
        #pragma unroll
        for (int mth = 0; mth < 4; ++mth)
            T[(h2 * 32 + j * 4 + mth) * 136 + ci] = f2bf(v[mth]);
    }
    __syncthreads();
    #pragma unroll
    for (int k = 0; k < 4; ++k) {
        int idx = tid + k * 256;
        int p = idx >> 4, c8 = idx & 15;
        int gp = p0 + p;
        int h = gp / 56, w = gp - h * 56;
        size_t site = (size_t)(n * PADW + 1 + h) * PADW + 1 + w;
        *(s16x8*)(XtP + site * 128 + c8 * 8) = *(const s16x8*)&T[p * 136 + c8 * 8];
    }
}

// ---------------------------------------------------------------------------
// Kernel 4: implicit-GEMM conv — 128co x 8rows, 8 waves, wave = 64co x 2rows
// with WRAP-AROUND B-fragments: 112 outputs = 7 frags of 16, ZERO N-padding
// (28 MFMA/tap/wave, -12.5% MFMA and B-reads). A: single 73.7KB buffer,
// restaged at chunk boundary (barrier -> 9 gloads -> vmcnt(0) -> barrier).
// B: double-buffered 2x41KB, staged 1 chunk ahead. r9-style asm lookahead:
// 11 DSR for tap t+1, lgkmcnt(11), 28 MFMA. One barrier pair per chunk.
// FIX vs r13: BRD macro parenthesization — (TT/3) expanded as T + 1/3 when
// called with T+1, corrupting every lookahead tap offset.
// ---------------------------------------------------------------------------
__global__ __launch_bounds__(512, 2) void conv_mfma(const u16* __restrict__ XtP,
                                                    const u16* __restrict__ Apack,
                                                    float* __restrict__ out) {
    __shared__ u16 Alds[36864];        // 73,728 B : [128 row][288 k] linear
    __shared__ u16 Xlds[2][20480];     // 2 x 40,960 B : [640 site][32 ci]

    const int tid  = threadIdx.x;
    const int wid  = tid >> 6;
    const int lane = tid & 63;
    const int r16  = lane & 15;
    const int kg   = lane >> 4;
    const int cohalf = wid >> 2;       // 0..1 : 64-co half
    const int rp     = wid & 3;        // 0..3 : row-pair

    // XCD swizzle: 448 blocks, 56 per XCD (bijective)
    const int bid = blockIdx.x;
    const int s   = (bid & 7) * 56 + (bid >> 3);
    const int n   = s / 14;
    const int rem = s - n * 14;
    const int by  = rem >> 1;          // 0..6
    const int bx  = rem & 1;           // 0..1
    const int co0 = bx * 128;
    const int h0  = by * 8;

    f32x4 acc[4][7];
    #pragma unroll
    for (int i = 0; i < 4; ++i)
        #pragma unroll
        for (int j = 0; j < 7; ++j) acc[i][j] = (f32x4){0.f, 0.f, 0.f, 0.f};

    // ---- B-staging source offsets (u16 units, sans cc term) ----
    const int hbase = n * PADW + h0;
    unsigned int bsrc[5];
    #pragma unroll
    for (int i = 0; i < 5; ++i) {
        int p  = i * 512 + tid;
        int pc = (p < 2320) ? p : (p - 2320);       // clamp tail to valid sites
        int site = pc >> 2, gg = pc & 3;
        int r = site / 58, cl = site - r * 58;
        int g2 = gg ^ ((site >> 1) & 3);
        bsrc[i] = (unsigned)(((hbase + r) * PADW + cl) * 128 + g2 * 8);
    }

    // ---- A fragment LDS base (bytes): swizzle invariant in cohalf/mf/tap ----
    lcv AbL = (lcv)((const char*)&Alds[0] + cohalf * 36864
                    + (r16 * 288 + ((kg ^ ((r16 >> 1) & 3)) << 3)) * 2);

    // ---- B wrap-fragment base sites: o = nf*16+r16 -> (row, col) in wave tile
    int sb[7], orow7[7], ocol7[7];
    #pragma unroll
    for (int nf = 0; nf < 7; ++nf) {
        int o = nf * 16 + r16;
        int orw = (o >= 56) ? 1 : 0;
        int ocl = o - 56 * orw;
        orow7[nf] = orw; ocol7[nf] = ocl;
        sb[nf] = (rp * 2 + orw) * 58 + ocl;   // site at dh=dw=0
    }

    // ---- prologue: stage A[0] + B[0], drain, barrier ----
    {
        const u16* asrc = Apack + (size_t)bx * 36864;
        #pragma unroll
        for (int i = 0; i < 9; ++i)
            GLOAD16(asrc + (size_t)(i * 512 + tid) * 8, &Alds[(i * 512 + wid * 64) * 8]);
        #pragma unroll
        for (int i = 0; i < 5; ++i)
            GLOAD16(XtP + (size_t)bsrc[i], &Xlds[0][(i * 512 + wid * 64) * 8]);
        asm volatile("s_waitcnt vmcnt(0)" ::: "memory");
        __builtin_amdgcn_s_barrier();
        __builtin_amdgcn_sched_barrier(0);
    }

    i32x4 af[2][4], bf[2][7];

    // B-read burst for tap TT into set SS (7 frags, wrap addressing)
#define BRD(SS, TT)                                                           \
    {                                                                         \
        const int dt_ = (((TT)) / 3) * 58 + (((TT)) % 3);                     \
        _Pragma("unroll")                                                     \
        for (int nf = 0; nf < 7; ++nf) {                                      \
            int site_ = sb[nf] + dt_;                                         \
            int off_  = (site_ << 6) + ((kg ^ ((site_ >> 1) & 3)) << 4);      \
            lcv xb_ = (lcv)(xcur + off_);                                     \
            DSR(bf[SS][nf], xb_, 0);                                          \
        }                                                                     \
    }
#define ARD(SS, TT)                                                           \
    {                                                                         \
        DSR(af[SS][0], AbL, 0 * 9216 + ((TT)) * 64);                          \
        DSR(af[SS][1], AbL, 1 * 9216 + ((TT)) * 64);                          \
        DSR(af[SS][2], AbL, 2 * 9216 + ((TT)) * 64);                          \
        DSR(af[SS][3], AbL, 3 * 9216 + ((TT)) * 64);                          \
    }

#define CHUNK(CC, LAST)                                                       \
  {                                                                           \
    const char* xcur = (const char*)&Xlds[(CC) & 1][0];                       \
    if (!(LAST)) {                                                            \
      _Pragma("unroll")                                                       \
      for (int i = 0; i < 5; ++i)                                             \
        GLOAD16(XtP + (size_t)bsrc[i] + ((CC) + 1) * 32,                      \
                &Xlds[((CC) + 1) & 1][(i * 512 + wid * 64) * 8]);             \
    }                                                                         \
    ARD(0, 0) BRD(0, 0)                                                       \
    __builtin_amdgcn_sched_barrier(0);                                        \
    _Pragma("unroll")                                                         \
    for (int T = 0; T < 9; ++T) {                                             \
      const int cs = T & 1, ns = cs ^ 1;                                      \
      if (T < 8) {                                                            \
        ARD(ns, (T + 1)) BRD(ns, (T + 1))                                     \
        asm volatile("s_waitcnt lgkmcnt(11)" ::: "memory");                   \
      } else {                                                                \
        asm volatile("s_waitcnt lgkmcnt(0)" ::: "memory");                    \
      }                                                                       \
      __builtin_amdgcn_sched_barrier(0);                                      \
      __builtin_amdgcn_s_setprio(1);                                          \
      _Pragma("unroll")                                                       \
      for (int mf = 0; mf < 4; ++mf)                                          \
        _Pragma("unroll")                                                     \
        for (int nf = 0; nf < 7; ++nf)                                        \
          acc[mf][nf] = __builtin_amdgcn_mfma_f32_16x16x32_bf16(              \
              as_h(af[cs][mf]), as_h(bf[cs][nf]), acc[mf][nf], 0, 0, 0);      \
      __builtin_amdgcn_s_setprio(0);                                          \
      __builtin_amdgcn_sched_barrier(0);                                      \
    }                                                                         \
    if (!(LAST)) {                                                            \
      __builtin_amdgcn_s_barrier();   /* all waves done reading Alds/B[CC] */ \
      const u16* asrcN = Apack + (size_t)(((CC) + 1) * 2 + bx) * 36864;       \
      _Pragma("unroll")                                                       \
      for (int i = 0; i < 9; ++i)                                             \
        GLOAD16(asrcN + (size_t)(i * 512 + tid) * 8,                          \
                &Alds[(i * 512 + wid * 64) * 8]);                             \
      asm volatile("s_waitcnt vmcnt(0)" ::: "memory");                        \
      __builtin_amdgcn_s_barrier();                                           \
      __builtin_amdgcn_sched_barrier(0);                                      \
    }                                                                         \
  }

    CHUNK(0, false)
    CHUNK(1, false)
    CHUNK(2, false)
    CHUNK(3, true)
#undef CHUNK
#undef ARD
#undef BRD

    // ---- store (wrap-frags: fully dense, no mask) ----
    #pragma unroll
    for (int mf = 0; mf < 4; ++mf)
        #pragma unroll
        for (int nf = 0; nf < 7; ++nf) {
            int h = h0 + rp * 2 + orow7[nf];
            float* op = out + ((size_t)(n * COUT + co0 + cohalf * 64 + mf * 16
                                        + kg * 4)) * HWSZ + h * WW + ocol7[nf];
            #pragma unroll
            for (int j = 0; j < 4; ++j)
                op[(size_t)j * HWSZ] = acc[mf][nf][j];
        }
}

// ---------------------------------------------------------------------------
// Launch
// ---------------------------------------------------------------------------
extern "C" void kernel_launch(void* const* d_in, const int* in_sizes, int n_in,
                              void* d_out, int out_size, void* d_ws, size_t ws_size,
                              hipStream_t stream) {
    const float* X      = (const float*)d_in[0];
    const float* weight = (const float*)d_in[1];
    // Wp (d_in[2]) never enters the forward (faithful to source)
    const float* Wn     = (const float*)d_in[3];
    float* out = (float*)d_out;

    float* ws_partial = (float*)d_ws;                        // 256 f32
    u16*   ws_apack   = (u16*)((char*)d_ws + 4096);          // 294912 u16
    u16*   ws_xtp     = (u16*)((char*)d_ws + (1 << 20));     // 32*3364*128 u16 (~27.5 MB)

    maxabs_part<<<256, 256, 0, stream>>>(weight, ws_partial);
    quant_pack<<<WELEM / 256, 256, 0, stream>>>(weight, ws_partial, Wn, ws_apack);
    x_to_bf16t<<<B_ * (HWSZ / 64), 256, 0, stream>>>(X, ws_xtp);

    conv_mfma<<<448, 512, 0, stream>>>(ws_xtp, ws_apack, out);
}

// Round 15
// 88.390 us; speedup vs baseline: 1.8173x; 1.8173x over previous
//
#include <hip/hip_runtime.h>
#include <hip/hip_bf16.h>

#define THRESH 0.05f
constexpr int B_   = 32;
constexpr int CIN  = 128;
constexpr int COUT = 256;
constexpr int HH   = 56;
constexpr int WW   = 56;
constexpr int HWSZ = HH * WW;            // 3136
constexpr int WELEM = COUT * CIN * 9;    // 294912
constexpr int PADW = 58;                 // padded spatial dim

typedef unsigned short u16;
typedef __attribute__((ext_vector_type(4))) float  f32x4;
typedef __attribute__((ext_vector_type(8))) short  s16x8;
typedef __attribute__((ext_vector_type(4))) int    i32x4;

typedef const __attribute__((address_space(1))) void* gas1;
typedef __attribute__((address_space(3))) void* las3;
typedef const __attribute__((address_space(3))) void* lcv;
#define GLOAD16(gsrc, ldst) \
    __builtin_amdgcn_global_load_lds((gas1)(gsrc), (las3)(ldst), 16, 0, 0)

// opaque LDS vector read: compiler cannot sink/fold/remat
#define DSR(dst, base, byteoff) \
    asm volatile("ds_read_b128 %0, %1 offset:%2" : "=v"(dst) : "v"(base), "i"(byteoff))

static __device__ __forceinline__ u16 f2bf(float f) {
    __hip_bfloat16 h = __float2bfloat16(f);
    return *reinterpret_cast<u16*>(&h);
}
static __device__ __forceinline__ s16x8 as_h(i32x4 v) {
    s16x8 r; __builtin_memcpy(&r, &v, 16); return r;
}

// ---------------------------------------------------------------------------
// Kernel 1: per-block maxabs partials
// ---------------------------------------------------------------------------
__global__ __launch_bounds__(256) void maxabs_part(const float* __restrict__ w,
                                                   float* __restrict__ partial) {
    int tid = threadIdx.x;
    float m = 0.0f;
    for (int i = blockIdx.x * 256 + tid; i < WELEM; i += 256 * 256)
        m = fmaxf(m, fabsf(w[i]));
    #pragma unroll
    for (int off = 32; off > 0; off >>= 1) m = fmaxf(m, __shfl_xor(m, off));
    __shared__ float s[4];
    if ((tid & 63) == 0) s[tid >> 6] = m;
    __syncthreads();
    if (tid == 0) partial[blockIdx.x] = fmaxf(fmaxf(s[0], s[1]), fmaxf(s[2], s[3]));
}

// ---------------------------------------------------------------------------
// Kernel 2: reduce + faithful ternary quantize + pack bf16 into PERMUTED layout
// Apack u16 index: ((cc*4 + cot)*64 + row)*288 + tap*32 + (g ^ ((row>>1)&3))*8 + e
// ---------------------------------------------------------------------------
__global__ __launch_bounds__(256) void quant_pack(const float* __restrict__ w,
                                                  const float* __restrict__ partial,
                                                  const float* __restrict__ Wn,
                                                  u16* __restrict__ Apack) {
    int tid = threadIdx.x;
    float m = partial[tid];
    #pragma unroll
    for (int off = 32; off > 0; off >>= 1) m = fmaxf(m, __shfl_xor(m, off));
    __shared__ float s[4];
    if ((tid & 63) == 0) s[tid >> 6] = m;
    __syncthreads();
    const float mx = fmaxf(fmaxf(s[0], s[1]), fmaxf(s[2], s[3]));
    const float wn = Wn[0];

    int idx = blockIdx.x * 256 + tid;          // ((co*128+ci)*9+tap)
    float nw = w[idx] / mx;
    float q  = (nw > -THRESH && nw <= THRESH) ? 0.0f : nw;
    if (q >  THRESH) q =  1.0f;
    if (q < -THRESH) q = -1.0f;
    if (q == -1.0f)  q = wn;

    int tap = idx % 9;
    int r   = idx / 9;
    int ci  = r % CIN;
    int co  = r / CIN;
    int cc  = ci >> 5, lci = ci & 31, g = lci >> 3, e = lci & 7;
    int cot = co >> 6, row = co & 63;
    int swz = g ^ ((row >> 1) & 3);
    Apack[(size_t)((cc * 4 + cot) * 64 + row) * 288 + tap * 32 + swz * 8 + e] = f2bf(q);
}

// ---------------------------------------------------------------------------
// Kernel 3: X (NCHW f32) -> padded Xt[n][1+h][1+w][ci] bf16 via LDS transpose.
// Blocks with pt==0 additionally zero the padded borders for their image.
// ---------------------------------------------------------------------------
__global__ __launch_bounds__(256) void x_to_bf16t(const float* __restrict__ X,
                                                  u16* __restrict__ XtP) {
    __shared__ u16 T[64 * 136];
    const int b  = blockIdx.x;
    const int n  = b / 49, pt = b - n * 49;
    const int p0 = pt * 64;
    const int tid = threadIdx.x;
    const int ci  = tid >> 1, h2 = tid & 1;

    if (pt == 0) {
        for (int idx = tid; idx < 3648; idx += 256) {
            int c16 = idx & 15, s = idx >> 4;
            int r, c;
            if      (s < 58)  { r = 0;           c = s; }
            else if (s < 116) { r = 57;          c = s - 58; }
            else if (s < 172) { r = s - 116 + 1; c = 0; }
            else              { r = s - 172 + 1; c = 57; }
            size_t site = (size_t)(n * PADW + r) * PADW + c;
            *(s16x8*)(XtP + site * 128 + c16 * 8) = (s16x8){0,0,0,0,0,0,0,0};
        }
    }

    const float* src = X + ((size_t)(n * CIN + ci)) * HWSZ + p0 + h2 * 32;
    #pragma unroll
    for (int j = 0; j < 8; ++j) {
        f32x4 v = *(const f32x4*)(src + j * 4);
        #pragma unroll
        for (int mth = 0; mth < 4; ++mth)
            T[(h2 * 32 + j * 4 + mth) * 136 + ci] = f2bf(v[mth]);
    }
    __syncthreads();
    #pragma unroll
    for (int k = 0; k < 4; ++k) {
        int idx = tid + k * 256;
        int p = idx >> 4, c8 = idx & 15;
        int gp = p0 + p;
        int h = gp / 56, w = gp - h * 56;
        size_t site = (size_t)(n * PADW + 1 + h) * PADW + 1 + w;
        *(s16x8*)(XtP + site * 128 + c8 * 8) = *(const s16x8*)&T[p * 136 + c8 * 8];
    }
}

// ---------------------------------------------------------------------------
// Kernel 4: implicit-GEMM conv — r9 structure (64co x 8rows, 896 blocks,
// double-buffered A+B LDS, one barrier per chunk) with the lookahead DEEPENED
// to 2 taps: 3 fragment sets, ~16 outstanding DSRs at each wait. Per tap:
// [asm ds_read x8 for tap t+2] -> s_waitcnt lgkmcnt(15) (4-bit max; waits
// tap t's reads) -> sched_barrier(0) -> 16 MFMA on tap t. Register-reuse
// distance (set overwritten one cluster after consumption) identical to r9.
// ---------------------------------------------------------------------------
__global__ __launch_bounds__(512, 2) void conv_mfma(const u16* __restrict__ XtP,
                                                    const u16* __restrict__ Apack,
                                                    float* __restrict__ out) {
    __shared__ u16 Alds[2][18432];     // 2 x 36,864 B : [64 row][288 k] linear
    __shared__ u16 Xlds[2][20480];     // 2 x 40,960 B : [640 site][32 ci] linear

    const int tid  = threadIdx.x;
    const int wid  = tid >> 6;
    const int lane = tid & 63;
    const int r16  = lane & 15;
    const int g    = lane >> 4;

    // XCD swizzle: 896 blocks, 112 per XCD -> XCD x owns images 4x..4x+3
    const int bid = blockIdx.x;
    const int s   = (bid & 7) * 112 + (bid >> 3);
    const int n   = s / 28;
    const int rem = s - n * 28;
    const int by  = rem >> 2;
    const int bx  = rem & 3;
    const int co0 = bx * 64;
    const int h0  = by * 8;

    f32x4 acc[4][4];
    #pragma unroll
    for (int i = 0; i < 4; ++i)
        #pragma unroll
        for (int j = 0; j < 4; ++j) acc[i][j] = (f32x4){0.f, 0.f, 0.f, 0.f};

    // ---- B-staging source offsets (u16 units, sans cc term) ----
    const int hbase = n * PADW + h0;
    unsigned int bsrc[5];
    #pragma unroll
    for (int i = 0; i < 5; ++i) {
        int p  = i * 512 + tid;
        int pc = (p < 2320) ? p : (p - 2320);       // clamp tail to valid sites
        int site = pc >> 2, gg = pc & 3;
        int r = site / 58, c = site - r * 58;
        int g2 = gg ^ ((site >> 1) & 3);
        bsrc[i] = (unsigned)(((hbase + r) * PADW + c) * 128 + g2 * 8);
    }

    // ---- A fragment base (BYTES): XOR term invariant in mf & tap ----
    const int abase0B = (r16 * 288 + ((g ^ ((r16 >> 1) & 3)) << 3)) * 2;

    // ---- B per-tap offsets (BYTES): XOR term invariant in nf ----
    int otapB[9];
    #pragma unroll
    for (int t = 0; t < 9; ++t) {
        int base_t = (wid + t / 3) * 58 + r16 + (t % 3);
        otapB[t] = (base_t * 32 + ((g ^ ((base_t >> 1) & 3)) << 3)) * 2;
    }

    // ---- prologue: stage chunk 0 into buffer 0, full drain ----
    {
        const u16* asrc = Apack + (size_t)bx * 18432;
        #pragma unroll
        for (int i = 0; i < 4; ++i)
            GLOAD16(asrc + (size_t)(i * 512 + tid) * 8, &Alds[0][(i * 512 + wid * 64) * 8]);
        if (wid < 4)
            GLOAD16(asrc + (size_t)(2048 + wid * 64 + lane) * 8, &Alds[0][(2048 + wid * 64) * 8]);
        #pragma unroll
        for (int i = 0; i < 5; ++i)
            GLOAD16(XtP + (size_t)bsrc[i], &Xlds[0][(i * 512 + wid * 64) * 8]);
        asm volatile("s_waitcnt vmcnt(0)" ::: "memory");
        __builtin_amdgcn_s_barrier();
        __builtin_amdgcn_sched_barrier(0);
    }

    #pragma unroll
    for (int cc = 0; cc < 4; ++cc) {
        const int cur = cc & 1;
        const int nxt = cur ^ 1;

        // ---- issue ALL staging for chunk cc+1 (vmem pipe, independent) ----
        if (cc < 3) {
            const u16* asrc_n = Apack + (size_t)((cc + 1) * 4 + bx) * 18432;
            #pragma unroll
            for (int i = 0; i < 4; ++i)
                GLOAD16(asrc_n + (size_t)(i * 512 + tid) * 8,
                        &Alds[nxt][(i * 512 + wid * 64) * 8]);
            if (wid < 4)
                GLOAD16(asrc_n + (size_t)(2048 + wid * 64 + lane) * 8,
                        &Alds[nxt][(2048 + wid * 64) * 8]);
            #pragma unroll
            for (int i = 0; i < 5; ++i)
                GLOAD16(XtP + (size_t)bsrc[i] + (cc + 1) * 32,
                        &Xlds[nxt][(i * 512 + wid * 64) * 8]);
        }

        // ---- asm ds_read pipelined 9-tap stream, depth 2 (3 sets) ----
        lcv Ab = (lcv)((const char*)&Alds[cur][0] + abase0B);
        const char* XbG = (const char*)&Xlds[cur][0];

        i32x4 af[3][4], bf[3][4];
        {   // preload taps 0 and 1
            lcv xb0 = (lcv)(XbG + otapB[0]);
            DSR(af[0][0], Ab, 0 * 9216 + 0 * 64);
            DSR(af[0][1], Ab, 1 * 9216 + 0 * 64);
            DSR(af[0][2], Ab, 2 * 9216 + 0 * 64);
            DSR(af[0][3], Ab, 3 * 9216 + 0 * 64);
            DSR(bf[0][0], xb0, 0);
            DSR(bf[0][1], xb0, 1024);
            DSR(bf[0][2], xb0, 2048);
            DSR(bf[0][3], xb0, 3072);
            lcv xb1 = (lcv)(XbG + otapB[1]);
            DSR(af[1][0], Ab, 0 * 9216 + 1 * 64);
            DSR(af[1][1], Ab, 1 * 9216 + 1 * 64);
            DSR(af[1][2], Ab, 2 * 9216 + 1 * 64);
            DSR(af[1][3], Ab, 3 * 9216 + 1 * 64);
            DSR(bf[1][0], xb1, 0);
            DSR(bf[1][1], xb1, 1024);
            DSR(bf[1][2], xb1, 2048);
            DSR(bf[1][3], xb1, 3072);
        }

        #pragma unroll
        for (int t = 0; t < 9; ++t) {
            const int c  = t % 3;
            const int n2 = (t + 2) % 3;
            if (t < 7) {
                lcv xb = (lcv)(XbG + otapB[t + 2]);
                DSR(af[n2][0], Ab, 0 * 9216 + (t + 2) * 64);
                DSR(af[n2][1], Ab, 1 * 9216 + (t + 2) * 64);
                DSR(af[n2][2], Ab, 2 * 9216 + (t + 2) * 64);
                DSR(af[n2][3], Ab, 3 * 9216 + (t + 2) * 64);
                DSR(bf[n2][0], xb, 0);
                DSR(bf[n2][1], xb, 1024);
                DSR(bf[n2][2], xb, 2048);
                DSR(bf[n2][3], xb, 3072);
                asm volatile("s_waitcnt lgkmcnt(15)" ::: "memory");
            } else if (t == 7) {
                asm volatile("s_waitcnt lgkmcnt(8)" ::: "memory");
            } else {
                asm volatile("s_waitcnt lgkmcnt(0)" ::: "memory");
            }
            __builtin_amdgcn_sched_barrier(0);   // rule 18: MFMAs stay below wait
            __builtin_amdgcn_s_setprio(1);
            #pragma unroll
            for (int mf = 0; mf < 4; ++mf)
                #pragma unroll
                for (int nf = 0; nf < 4; ++nf)
                    acc[mf][nf] = __builtin_amdgcn_mfma_f32_16x16x32_bf16(
                        as_h(af[c][mf]), as_h(bf[c][nf]), acc[mf][nf], 0, 0, 0);
            __builtin_amdgcn_s_setprio(0);
            __builtin_amdgcn_sched_barrier(0);   // keep next prefetch below MFMAs
        }

        // ---- chunk boundary: drain staging, one barrier, flip ----
        if (cc < 3) {
            asm volatile("s_waitcnt vmcnt(0)" ::: "memory");
            __builtin_amdgcn_s_barrier();
            __builtin_amdgcn_sched_barrier(0);
        }
    }

    // ---- store: D col = r16 (spatial), row = g*4+j (co) ----
    const int h = h0 + wid;
    float* obase = out + ((size_t)(n * COUT + co0)) * HWSZ + h * WW;
    #pragma unroll
    for (int mf = 0; mf < 4; ++mf)
        #pragma unroll
        for (int nf = 0; nf < 4; ++nf) {
            int col = nf * 16 + r16;
            if (col < WW) {
                #pragma unroll
                for (int j = 0; j < 4; ++j) {
                    int co = mf * 16 + g * 4 + j;
                    obase[(size_t)co * HWSZ + col] = acc[mf][nf][j];
                }
            }
        }
}

// ---------------------------------------------------------------------------
// Launch
// ---------------------------------------------------------------------------
extern "C" void kernel_launch(void* const* d_in, const int* in_sizes, int n_in,
                              void* d_out, int out_size, void* d_ws, size_t ws_size,
                              hipStream_t stream) {
    const float* X      = (const float*)d_in[0];
    const float* weight = (const float*)d_in[1];
    // Wp (d_in[2]) never enters the forward (faithful to source)
    const float* Wn     = (const float*)d_in[3];
    float* out = (float*)d_out;

    float* ws_partial = (float*)d_ws;                        // 256 f32
    u16*   ws_apack   = (u16*)((char*)d_ws + 4096);          // 294912 u16
    u16*   ws_xtp     = (u16*)((char*)d_ws + (1 << 20));     // 32*3364*128 u16 (~27.5 MB)

    maxabs_part<<<256, 256, 0, stream>>>(weight, ws_partial);
    quant_pack<<<WELEM / 256, 256, 0, stream>>>(weight, ws_partial, Wn, ws_apack);
    x_to_bf16t<<<B_ * (HWSZ / 64), 256, 0, stream>>>(X, ws_xtp);

    conv_mfma<<<896, 512, 0, stream>>>(ws_xtp, ws_apack, out);
}